// Round 1
// baseline (805.427 us; speedup 1.0000x reference)
//
#include <hip/hip_runtime.h>
#include <math.h>

#define BATCH   2048
#define NROWS   4096   // 2*BATCH
#define LATENT  2048
#define PROJ    256
#define TEMP_INV 2.0f      // 1/0.5
#define BN_EPS  1e-5f
#define COS_EPS 1e-8f

// ---------------------------------------------------------------------------
// GEMM1: X[m][n] = sum_k H[m][k] * W1[n][k]   (M=4096, N=2048, K=2048)
// H = concat(h_i, h_j) by rows. Classic 64x64x16 LDS tile, 4x4 microtile.
// ---------------------------------------------------------------------------
__global__ __launch_bounds__(256) void gemm1_kernel(
    const float* __restrict__ hi, const float* __restrict__ hj,
    const float* __restrict__ W1, float* __restrict__ X)
{
    __shared__ __align__(16) float As[16][68];
    __shared__ __align__(16) float Bs[16][68];
    const int tid = threadIdx.x;
    const int m0 = blockIdx.y * 64;
    const int n0 = blockIdx.x * 64;
    const int lm = tid >> 2;      // 0..63  tile row for staging
    const int kq = tid & 3;       // 0..3   which float4 along k
    const int tx = tid & 15;      // micro col group
    const int ty = tid >> 4;      // micro row group
    // tile lies entirely in one half (64 | 2048)
    const float* Abase = (m0 < BATCH) ? (hi + (size_t)m0 * LATENT)
                                      : (hj + (size_t)(m0 - BATCH) * LATENT);
    const float* Bbase = W1 + (size_t)n0 * LATENT;
    float acc[4][4] = {};
    for (int k0 = 0; k0 < LATENT; k0 += 16) {
        __syncthreads();
        float4 av = *reinterpret_cast<const float4*>(Abase + lm * LATENT + k0 + kq * 4);
        float4 bv = *reinterpret_cast<const float4*>(Bbase + lm * LATENT + k0 + kq * 4);
        As[kq*4+0][lm] = av.x; As[kq*4+1][lm] = av.y;
        As[kq*4+2][lm] = av.z; As[kq*4+3][lm] = av.w;
        Bs[kq*4+0][lm] = bv.x; Bs[kq*4+1][lm] = bv.y;
        Bs[kq*4+2][lm] = bv.z; Bs[kq*4+3][lm] = bv.w;
        __syncthreads();
        #pragma unroll
        for (int k = 0; k < 16; ++k) {
            float4 a = *reinterpret_cast<const float4*>(&As[k][ty * 4]);
            float4 b = *reinterpret_cast<const float4*>(&Bs[k][tx * 4]);
            float aa[4] = {a.x, a.y, a.z, a.w};
            float bb[4] = {b.x, b.y, b.z, b.w};
            #pragma unroll
            for (int i = 0; i < 4; ++i)
                #pragma unroll
                for (int j = 0; j < 4; ++j)
                    acc[i][j] = fmaf(aa[i], bb[j], acc[i][j]);
        }
    }
    #pragma unroll
    for (int i = 0; i < 4; ++i) {
        int row = m0 + ty * 4 + i;
        float4 v = make_float4(acc[i][0], acc[i][1], acc[i][2], acc[i][3]);
        *reinterpret_cast<float4*>(X + (size_t)row * LATENT + n0 + tx * 4) = v;
    }
}

// ---------------------------------------------------------------------------
// BN stats: per-half (2048 rows each), per-column sum and sum-of-squares.
// grid (LATENT/256, 32): by = row chunk of 128 rows; half = by>>4.
// ---------------------------------------------------------------------------
__global__ __launch_bounds__(256) void bn_stats_kernel(
    const float* __restrict__ X, float* __restrict__ sums, float* __restrict__ sumsqs)
{
    const int c = blockIdx.x * 256 + threadIdx.x;
    const int chunk = blockIdx.y;          // 0..31
    const int half = chunk >> 4;
    const int r0 = chunk * 128;
    float s = 0.f, q = 0.f;
    for (int r = 0; r < 128; ++r) {
        float v = X[(size_t)(r0 + r) * LATENT + c];
        s += v;
        q += v * v;
    }
    atomicAdd(&sums[half * LATENT + c], s);
    atomicAdd(&sumsqs[half * LATENT + c], q);
}

// scale/shift: xn = relu(x*scale + shift)
__global__ __launch_bounds__(256) void bn_final_kernel(
    const float* __restrict__ sums, const float* __restrict__ sumsqs,
    const float* __restrict__ gamma, const float* __restrict__ beta,
    float* __restrict__ scaleA, float* __restrict__ shiftA)
{
    const int idx = blockIdx.x * 256 + threadIdx.x;   // 0..4095
    const int c = idx & (LATENT - 1);
    float mu  = sums[idx] * (1.0f / BATCH);
    float var = sumsqs[idx] * (1.0f / BATCH) - mu * mu;
    float inv = rsqrtf(var + BN_EPS);
    float sc = gamma[c] * inv;
    scaleA[idx] = sc;
    shiftA[idx] = beta[c] - mu * sc;
}

// ---------------------------------------------------------------------------
// GEMM2: Z[m][n] = sum_k relu(X[m][k]*scale+shift) * W2[n][k] + b2[n]
// M=4096, N=256, K=2048. BN+ReLU fused into the A-tile load.
// ---------------------------------------------------------------------------
__global__ __launch_bounds__(256) void gemm2_kernel(
    const float* __restrict__ X, const float* __restrict__ W2,
    const float* __restrict__ b2, const float* __restrict__ scaleA,
    const float* __restrict__ shiftA, float* __restrict__ Z)
{
    __shared__ __align__(16) float As[16][68];
    __shared__ __align__(16) float Bs[16][68];
    const int tid = threadIdx.x;
    const int m0 = blockIdx.y * 64;
    const int n0 = blockIdx.x * 64;
    const int lm = tid >> 2, kq = tid & 3;
    const int tx = tid & 15, ty = tid >> 4;
    const int half = (m0 >= BATCH) ? 1 : 0;
    const float* sc = scaleA + half * LATENT;
    const float* sh = shiftA + half * LATENT;
    const float* Abase = X + (size_t)m0 * LATENT;
    const float* Bbase = W2 + (size_t)n0 * LATENT;
    float acc[4][4] = {};
    for (int k0 = 0; k0 < LATENT; k0 += 16) {
        __syncthreads();
        float4 av = *reinterpret_cast<const float4*>(Abase + lm * LATENT + k0 + kq * 4);
        float4 sv = *reinterpret_cast<const float4*>(sc + k0 + kq * 4);
        float4 hv = *reinterpret_cast<const float4*>(sh + k0 + kq * 4);
        av.x = fmaxf(fmaf(av.x, sv.x, hv.x), 0.f);
        av.y = fmaxf(fmaf(av.y, sv.y, hv.y), 0.f);
        av.z = fmaxf(fmaf(av.z, sv.z, hv.z), 0.f);
        av.w = fmaxf(fmaf(av.w, sv.w, hv.w), 0.f);
        float4 bv = *reinterpret_cast<const float4*>(Bbase + lm * LATENT + k0 + kq * 4);
        As[kq*4+0][lm] = av.x; As[kq*4+1][lm] = av.y;
        As[kq*4+2][lm] = av.z; As[kq*4+3][lm] = av.w;
        Bs[kq*4+0][lm] = bv.x; Bs[kq*4+1][lm] = bv.y;
        Bs[kq*4+2][lm] = bv.z; Bs[kq*4+3][lm] = bv.w;
        __syncthreads();
        #pragma unroll
        for (int k = 0; k < 16; ++k) {
            float4 a = *reinterpret_cast<const float4*>(&As[k][ty * 4]);
            float4 b = *reinterpret_cast<const float4*>(&Bs[k][tx * 4]);
            float aa[4] = {a.x, a.y, a.z, a.w};
            float bb[4] = {b.x, b.y, b.z, b.w};
            #pragma unroll
            for (int i = 0; i < 4; ++i)
                #pragma unroll
                for (int j = 0; j < 4; ++j)
                    acc[i][j] = fmaf(aa[i], bb[j], acc[i][j]);
        }
    }
    #pragma unroll
    for (int i = 0; i < 4; ++i) {
        int row = m0 + ty * 4 + i;
        int col = n0 + tx * 4;
        float4 v = make_float4(acc[i][0] + b2[col + 0], acc[i][1] + b2[col + 1],
                               acc[i][2] + b2[col + 2], acc[i][3] + b2[col + 3]);
        *reinterpret_cast<float4*>(Z + (size_t)row * PROJ + col) = v;
    }
}

// ---------------------------------------------------------------------------
// Row L2-normalize: zn[r] = z[r] / max(||z[r]||, COS_EPS). One wave per row.
// ---------------------------------------------------------------------------
__global__ __launch_bounds__(256) void rownorm_kernel(
    const float* __restrict__ Z, float* __restrict__ ZN)
{
    const int wave = threadIdx.x >> 6;
    const int lane = threadIdx.x & 63;
    const int row = blockIdx.x * 4 + wave;
    float v[4];
    float sq = 0.f;
    #pragma unroll
    for (int i = 0; i < 4; ++i) {
        v[i] = Z[(size_t)row * PROJ + lane + i * 64];
        sq += v[i] * v[i];
    }
    #pragma unroll
    for (int off = 32; off > 0; off >>= 1) sq += __shfl_xor(sq, off, 64);
    float inv = 1.0f / fmaxf(sqrtf(sq), COS_EPS);
    #pragma unroll
    for (int i = 0; i < 4; ++i)
        ZN[(size_t)row * PROJ + lane + i * 64] = v[i] * inv;
}

// ---------------------------------------------------------------------------
// sim tile + fused exp/row-sum. s[r][j] = 2*dot(zn[r],zn[j]).
// Per 64x64 tile: accumulate sum_j exp(s) per row (atomic), record diag exp
// and positive s (unique writers -> plain stores).
// ---------------------------------------------------------------------------
__global__ __launch_bounds__(256) void simlse_kernel(
    const float* __restrict__ ZN, float* __restrict__ rowsum,
    float* __restrict__ dgA, float* __restrict__ posA)
{
    __shared__ __align__(16) float As[16][68];
    __shared__ __align__(16) float Bs[16][68];
    __shared__ float Red[64][17];
    const int tid = threadIdx.x;
    const int r0 = blockIdx.y * 64;
    const int j0 = blockIdx.x * 64;
    const int lm = tid >> 2, kq = tid & 3;
    const int tx = tid & 15, ty = tid >> 4;
    float acc[4][4] = {};
    for (int k0 = 0; k0 < PROJ; k0 += 16) {
        __syncthreads();
        float4 av = *reinterpret_cast<const float4*>(ZN + (size_t)(r0 + lm) * PROJ + k0 + kq * 4);
        float4 bv = *reinterpret_cast<const float4*>(ZN + (size_t)(j0 + lm) * PROJ + k0 + kq * 4);
        As[kq*4+0][lm] = av.x; As[kq*4+1][lm] = av.y;
        As[kq*4+2][lm] = av.z; As[kq*4+3][lm] = av.w;
        Bs[kq*4+0][lm] = bv.x; Bs[kq*4+1][lm] = bv.y;
        Bs[kq*4+2][lm] = bv.z; Bs[kq*4+3][lm] = bv.w;
        __syncthreads();
        #pragma unroll
        for (int k = 0; k < 16; ++k) {
            float4 a = *reinterpret_cast<const float4*>(&As[k][ty * 4]);
            float4 b = *reinterpret_cast<const float4*>(&Bs[k][tx * 4]);
            float aa[4] = {a.x, a.y, a.z, a.w};
            float bb[4] = {b.x, b.y, b.z, b.w};
            #pragma unroll
            for (int i = 0; i < 4; ++i)
                #pragma unroll
                for (int j = 0; j < 4; ++j)
                    acc[i][j] = fmaf(aa[i], bb[j], acc[i][j]);
        }
    }
    float rsum[4];
    #pragma unroll
    for (int i = 0; i < 4; ++i) {
        int R = r0 + ty * 4 + i;
        int P = (R < BATCH) ? R + BATCH : R - BATCH;
        float t = 0.f;
        #pragma unroll
        for (int j = 0; j < 4; ++j) {
            int J = j0 + tx * 4 + j;
            float s = acc[i][j] * TEMP_INV;
            float e = expf(s);
            t += e;
            if (J == R) dgA[R] = e;     // unique writer
            if (J == P) posA[R] = s;    // unique writer
        }
        rsum[i] = t;
    }
    __syncthreads();
    #pragma unroll
    for (int i = 0; i < 4; ++i) Red[ty * 4 + i][tx] = rsum[i];
    __syncthreads();
    if (tid < 64) {
        float S = 0.f;
        #pragma unroll
        for (int t = 0; t < 16; ++t) S += Red[tid][t];
        atomicAdd(&rowsum[r0 + tid], S);
    }
}

// loss = (1/N) * sum_r [ log(rowsum_r - diag_r) - pos_r ]
__global__ __launch_bounds__(256) void loss_kernel(
    const float* __restrict__ rowsum, const float* __restrict__ dgA,
    const float* __restrict__ posA, float* __restrict__ out)
{
    __shared__ float red[256];
    float s = 0.f;
    for (int r = threadIdx.x; r < NROWS; r += 256)
        s += logf(rowsum[r] - dgA[r]) - posA[r];
    red[threadIdx.x] = s;
    __syncthreads();
    for (int off = 128; off > 0; off >>= 1) {
        if (threadIdx.x < off) red[threadIdx.x] += red[threadIdx.x + off];
        __syncthreads();
    }
    if (threadIdx.x == 0) out[0] = red[0] * (1.0f / NROWS);
}

// ---------------------------------------------------------------------------
extern "C" void kernel_launch(void* const* d_in, const int* in_sizes, int n_in,
                              void* d_out, int out_size, void* d_ws, size_t ws_size,
                              hipStream_t stream)
{
    const float* h_i   = (const float*)d_in[0];
    const float* h_j   = (const float*)d_in[1];
    const float* W1    = (const float*)d_in[2];
    const float* gamma = (const float*)d_in[3];
    const float* beta  = (const float*)d_in[4];
    const float* W2    = (const float*)d_in[5];
    const float* b2    = (const float*)d_in[6];
    float* out = (float*)d_out;

    // workspace layout (floats); ~41 MB total
    float* X      = (float*)d_ws;                       // 4096*2048
    float* Z      = X + (size_t)NROWS * LATENT;         // 4096*256
    float* ZN     = Z + (size_t)NROWS * PROJ;           // 4096*256
    float* sums   = ZN + (size_t)NROWS * PROJ;          // 2*2048
    float* sumsqs = sums + 2 * LATENT;                  // 2*2048
    float* rowsum = sumsqs + 2 * LATENT;                // 4096
    float* scaleA = rowsum + NROWS;                     // 2*2048
    float* shiftA = scaleA + 2 * LATENT;                // 2*2048
    float* dgA    = shiftA + 2 * LATENT;                // 4096
    float* posA   = dgA + NROWS;                        // 4096

    // zero the accumulators (sums, sumsqs, rowsum are contiguous)
    hipMemsetAsync(sums, 0, (size_t)(4 * LATENT + NROWS) * sizeof(float), stream);

    gemm1_kernel<<<dim3(LATENT / 64, NROWS / 64), 256, 0, stream>>>(h_i, h_j, W1, X);
    bn_stats_kernel<<<dim3(LATENT / 256, 32), 256, 0, stream>>>(X, sums, sumsqs);
    bn_final_kernel<<<dim3((2 * LATENT) / 256), 256, 0, stream>>>(sums, sumsqs, gamma, beta, scaleA, shiftA);
    gemm2_kernel<<<dim3(PROJ / 64, NROWS / 64), 256, 0, stream>>>(X, W2, b2, scaleA, shiftA, Z);
    rownorm_kernel<<<dim3(NROWS / 4), 256, 0, stream>>>(Z, ZN);
    simlse_kernel<<<dim3(NROWS / 64, NROWS / 64), 256, 0, stream>>>(ZN, rowsum, dgA, posA);
    loss_kernel<<<1, 256, 0, stream>>>(rowsum, dgA, posA, out);
}

// Round 2
// 242.301 us; speedup vs baseline: 3.3241x; 3.3241x over previous
//
#include <hip/hip_runtime.h>
#include <math.h>

#define BATCH   2048
#define NROWS   4096   // 2*BATCH
#define LATENT  2048
#define PROJ    256
#define TEMP_INV 2.0f      // 1/0.5
#define BN_EPS  1e-5f
#define COS_EPS 1e-8f

typedef __bf16 bf16x8 __attribute__((ext_vector_type(8)));
typedef float  f32x4  __attribute__((ext_vector_type(4)));

// fp32 -> bf16 round-to-nearest-even (inputs are finite; no NaN handling needed)
__device__ __forceinline__ unsigned short f2bf(float f) {
    union { float f; unsigned int u; } c; c.f = f;
    return (unsigned short)((c.u + 0x7FFFu + ((c.u >> 16) & 1u)) >> 16);
}

// async global->LDS, 16 bytes per lane. LDS dest must be wave-uniform base + lane*16.
__device__ __forceinline__ void gl_lds16(const unsigned short* g, unsigned short* l) {
    __builtin_amdgcn_global_load_lds(
        (__attribute__((address_space(1))) void*)g,
        (__attribute__((address_space(3))) void*)l, 16, 0, 0);
}

// ---------------------------------------------------------------------------
// fp32 -> bf16 bulk convert, 4 elems/thread
// ---------------------------------------------------------------------------
__global__ __launch_bounds__(256) void cvt_kernel(
    const float* __restrict__ src, unsigned short* __restrict__ dst, int n4)
{
    int i = blockIdx.x * 256 + threadIdx.x;
    if (i >= n4) return;
    float4 v = reinterpret_cast<const float4*>(src)[i];
    ushort4 o;
    o.x = f2bf(v.x); o.y = f2bf(v.y); o.z = f2bf(v.z); o.w = f2bf(v.w);
    reinterpret_cast<ushort4*>(dst)[i] = o;
}

// ---------------------------------------------------------------------------
// Core MFMA K-loop (m97 structure). 256 threads = 4 waves in 2x2.
// Tile: BM=WM*32 rows of A, BN=WN*32 rows of B, BK=32. Both operands are
// row-major [rows][K] bf16 (B^T-input GEMM). LDS tiles are row-major
// [rows][32] bf16, unpadded (global_load_lds constraint).
// ---------------------------------------------------------------------------
template<int K, int WM, int WN>
__device__ __forceinline__ void mfma_loop(
    const unsigned short* __restrict__ Ab,   // + m0*K already applied
    const unsigned short* __restrict__ Bb,   // + n0*K already applied
    unsigned short* As, unsigned short* Bs,
    f32x4 acc[WM][WN], int tid)
{
    constexpr int BM = WM * 32;
    constexpr int BN = WN * 32;
    const int wid = tid >> 6, lane = tid & 63;
    const int mblk = (wid >> 1) * (WM * 16);
    const int nblk = (wid & 1) * (WN * 16);
    const int lr = lane & 15, lk = lane >> 4;
    for (int k0 = 0; k0 < K; k0 += 32) {
        __syncthreads();   // previous iter's ds_reads done before overwrite
        #pragma unroll
        for (int u = 0; u < BM / 64; ++u) {
            int li = u * 256 + tid;
            gl_lds16(Ab + (size_t)(li >> 2) * K + k0 + (li & 3) * 8, As + li * 8);
        }
        #pragma unroll
        for (int u = 0; u < BN / 64; ++u) {
            int li = u * 256 + tid;
            gl_lds16(Bb + (size_t)(li >> 2) * K + k0 + (li & 3) * 8, Bs + li * 8);
        }
        __syncthreads();   // compiler drains vmcnt before barrier
        bf16x8 af[WM], bv[WN];
        #pragma unroll
        for (int i = 0; i < WM; ++i)
            af[i] = *reinterpret_cast<const bf16x8*>(As + (mblk + i * 16 + lr) * 32 + lk * 8);
        #pragma unroll
        for (int j = 0; j < WN; ++j)
            bv[j] = *reinterpret_cast<const bf16x8*>(Bs + (nblk + j * 16 + lr) * 32 + lk * 8);
        #pragma unroll
        for (int i = 0; i < WM; ++i)
            #pragma unroll
            for (int j = 0; j < WN; ++j)
                acc[i][j] = __builtin_amdgcn_mfma_f32_16x16x32_bf16(af[i], bv[j], acc[i][j], 0, 0, 0);
    }
}

// ---------------------------------------------------------------------------
// GEMM1: X[m][n] = sum_k H[m][k] * W1[n][k]  (M=4096, N=2048, K=2048), bf16 MFMA
// ---------------------------------------------------------------------------
__global__ __launch_bounds__(256) void gemm1_mfma(
    const unsigned short* __restrict__ Hb, const unsigned short* __restrict__ W1b,
    float* __restrict__ X)
{
    __shared__ __align__(16) unsigned short As[128 * 32];
    __shared__ __align__(16) unsigned short Bs[128 * 32];
    const int tid = threadIdx.x;
    const int m0 = blockIdx.y * 128, n0 = blockIdx.x * 128;
    f32x4 zero = {0.f, 0.f, 0.f, 0.f};
    f32x4 acc[4][4];
    #pragma unroll
    for (int i = 0; i < 4; ++i)
        #pragma unroll
        for (int j = 0; j < 4; ++j) acc[i][j] = zero;
    mfma_loop<LATENT, 4, 4>(Hb + (size_t)m0 * LATENT, W1b + (size_t)n0 * LATENT, As, Bs, acc, tid);
    const int wid = tid >> 6, lane = tid & 63;
    const int mblk = (wid >> 1) * 64, nblk = (wid & 1) * 64;
    const int lr = lane & 15, lq = lane >> 4;
    #pragma unroll
    for (int i = 0; i < 4; ++i)
        #pragma unroll
        for (int j = 0; j < 4; ++j)
            #pragma unroll
            for (int r = 0; r < 4; ++r) {
                int row = m0 + mblk + i * 16 + lq * 4 + r;
                int col = n0 + nblk + j * 16 + lr;
                X[(size_t)row * LATENT + col] = acc[i][j][r];
            }
}

// ---------------------------------------------------------------------------
// BN stats: per-half, per-column sum and sumsq over 2048 rows.
// ---------------------------------------------------------------------------
__global__ __launch_bounds__(256) void bn_stats_kernel(
    const float* __restrict__ X, float* __restrict__ sums, float* __restrict__ sumsqs)
{
    const int c = blockIdx.x * 256 + threadIdx.x;
    const int chunk = blockIdx.y;          // 0..31
    const int half = chunk >> 4;
    const int r0 = chunk * 128;
    float s = 0.f, q = 0.f;
    for (int r = 0; r < 128; ++r) {
        float v = X[(size_t)(r0 + r) * LATENT + c];
        s += v;
        q += v * v;
    }
    atomicAdd(&sums[half * LATENT + c], s);
    atomicAdd(&sumsqs[half * LATENT + c], q);
}

__global__ __launch_bounds__(256) void bn_final_kernel(
    const float* __restrict__ sums, const float* __restrict__ sumsqs,
    const float* __restrict__ gamma, const float* __restrict__ beta,
    float* __restrict__ scaleA, float* __restrict__ shiftA)
{
    const int idx = blockIdx.x * 256 + threadIdx.x;   // 0..4095
    const int c = idx & (LATENT - 1);
    float mu  = sums[idx] * (1.0f / BATCH);
    float var = sumsqs[idx] * (1.0f / BATCH) - mu * mu;
    float inv = rsqrtf(var + BN_EPS);
    float sc = gamma[c] * inv;
    scaleA[idx] = sc;
    shiftA[idx] = beta[c] - mu * sc;
}

// ---------------------------------------------------------------------------
// BN+ReLU applied to X, output bf16 Xb. 4 elems/thread.
// ---------------------------------------------------------------------------
__global__ __launch_bounds__(256) void bnrelu_cvt_kernel(
    const float* __restrict__ X, const float* __restrict__ scaleA,
    const float* __restrict__ shiftA, unsigned short* __restrict__ Xb)
{
    int i = blockIdx.x * 256 + threadIdx.x;      // group of 4
    int idx = i * 4;
    int row = idx >> 11;                          // / LATENT
    int col = idx & (LATENT - 1);
    int half = row >> 11;                         // / BATCH
    float4 x  = *reinterpret_cast<const float4*>(X + idx);
    float4 sc = *reinterpret_cast<const float4*>(scaleA + half * LATENT + col);
    float4 sh = *reinterpret_cast<const float4*>(shiftA + half * LATENT + col);
    ushort4 o;
    o.x = f2bf(fmaxf(fmaf(x.x, sc.x, sh.x), 0.f));
    o.y = f2bf(fmaxf(fmaf(x.y, sc.y, sh.y), 0.f));
    o.z = f2bf(fmaxf(fmaf(x.z, sc.z, sh.z), 0.f));
    o.w = f2bf(fmaxf(fmaf(x.w, sc.w, sh.w), 0.f));
    *reinterpret_cast<ushort4*>(Xb + idx) = o;
}

// ---------------------------------------------------------------------------
// GEMM2: Z[m][n] = sum_k Xb[m][k]*W2[n][k] + b2[n]  (M=4096, N=256, K=2048)
// BM=128, BN=64 tile -> 128 blocks.
// ---------------------------------------------------------------------------
__global__ __launch_bounds__(256) void gemm2_mfma(
    const unsigned short* __restrict__ Xb, const unsigned short* __restrict__ W2b,
    const float* __restrict__ b2, float* __restrict__ Z)
{
    __shared__ __align__(16) unsigned short As[128 * 32];
    __shared__ __align__(16) unsigned short Bs[64 * 32];
    const int tid = threadIdx.x;
    const int m0 = blockIdx.y * 128, n0 = blockIdx.x * 64;
    f32x4 zero = {0.f, 0.f, 0.f, 0.f};
    f32x4 acc[4][2];
    #pragma unroll
    for (int i = 0; i < 4; ++i) { acc[i][0] = zero; acc[i][1] = zero; }
    mfma_loop<LATENT, 4, 2>(Xb + (size_t)m0 * LATENT, W2b + (size_t)n0 * LATENT, As, Bs, acc, tid);
    const int wid = tid >> 6, lane = tid & 63;
    const int mblk = (wid >> 1) * 64, nblk = (wid & 1) * 32;
    const int lr = lane & 15, lq = lane >> 4;
    #pragma unroll
    for (int i = 0; i < 4; ++i)
        #pragma unroll
        for (int j = 0; j < 2; ++j)
            #pragma unroll
            for (int r = 0; r < 4; ++r) {
                int row = m0 + mblk + i * 16 + lq * 4 + r;
                int col = n0 + nblk + j * 16 + lr;
                Z[(size_t)row * PROJ + col] = acc[i][j][r] + b2[col];
            }
}

// ---------------------------------------------------------------------------
// Row L2-normalize Z -> bf16 ZNb. One wave per row.
// ---------------------------------------------------------------------------
__global__ __launch_bounds__(256) void rownorm_kernel(
    const float* __restrict__ Z, unsigned short* __restrict__ ZNb)
{
    const int wave = threadIdx.x >> 6;
    const int lane = threadIdx.x & 63;
    const int row = blockIdx.x * 4 + wave;
    float v[4];
    float sq = 0.f;
    #pragma unroll
    for (int i = 0; i < 4; ++i) {
        v[i] = Z[(size_t)row * PROJ + lane + i * 64];
        sq += v[i] * v[i];
    }
    #pragma unroll
    for (int off = 32; off > 0; off >>= 1) sq += __shfl_xor(sq, off, 64);
    float inv = 1.0f / fmaxf(sqrtf(sq), COS_EPS);
    #pragma unroll
    for (int i = 0; i < 4; ++i)
        ZNb[(size_t)row * PROJ + lane + i * 64] = f2bf(v[i] * inv);
}

// ---------------------------------------------------------------------------
// sim tile via MFMA + fused exp/rowsum/diag/pos. K=PROJ=256.
// ---------------------------------------------------------------------------
__global__ __launch_bounds__(256) void simlse_mfma(
    const unsigned short* __restrict__ ZNb, float* __restrict__ rowsum,
    float* __restrict__ dgA, float* __restrict__ posA)
{
    __shared__ __align__(16) unsigned short As[128 * 32];
    __shared__ __align__(16) unsigned short Bs[128 * 32];
    const int tid = threadIdx.x;
    const int r0 = blockIdx.y * 128, j0 = blockIdx.x * 128;
    f32x4 zero = {0.f, 0.f, 0.f, 0.f};
    f32x4 acc[4][4];
    #pragma unroll
    for (int i = 0; i < 4; ++i)
        #pragma unroll
        for (int j = 0; j < 4; ++j) acc[i][j] = zero;
    mfma_loop<PROJ, 4, 4>(ZNb + (size_t)r0 * PROJ, ZNb + (size_t)j0 * PROJ, As, Bs, acc, tid);
    const int wid = tid >> 6, lane = tid & 63;
    const int mblk = (wid >> 1) * 64, nblk = (wid & 1) * 64;
    const int lr = lane & 15, lq = lane >> 4;
    #pragma unroll
    for (int i = 0; i < 4; ++i)
        #pragma unroll
        for (int r = 0; r < 4; ++r) {
            int R = r0 + mblk + i * 16 + lq * 4 + r;
            int P = (R < BATCH) ? R + BATCH : R - BATCH;
            float t = 0.f;
            #pragma unroll
            for (int j = 0; j < 4; ++j) {
                int J = j0 + nblk + j * 16 + lr;
                float s = acc[i][j][r] * TEMP_INV;
                float e = __expf(s);
                t += e;
                if (J == R) dgA[R] = e;     // unique writer
                if (J == P) posA[R] = s;    // unique writer
            }
            // reduce across the 16 lanes sharing this row (flip bits of lane&15)
            t += __shfl_xor(t, 1, 64);
            t += __shfl_xor(t, 2, 64);
            t += __shfl_xor(t, 4, 64);
            t += __shfl_xor(t, 8, 64);
            if (lr == 0) atomicAdd(&rowsum[R], t);
        }
}

// loss = (1/N) * sum_r [ log(rowsum_r - diag_r) - pos_r ]
__global__ __launch_bounds__(256) void loss_kernel(
    const float* __restrict__ rowsum, const float* __restrict__ dgA,
    const float* __restrict__ posA, float* __restrict__ out)
{
    __shared__ float red[256];
    float s = 0.f;
    for (int r = threadIdx.x; r < NROWS; r += 256)
        s += logf(rowsum[r] - dgA[r]) - posA[r];
    red[threadIdx.x] = s;
    __syncthreads();
    for (int off = 128; off > 0; off >>= 1) {
        if (threadIdx.x < off) red[threadIdx.x] += red[threadIdx.x + off];
        __syncthreads();
    }
    if (threadIdx.x == 0) out[0] = red[0] * (1.0f / NROWS);
}

// ---------------------------------------------------------------------------
extern "C" void kernel_launch(void* const* d_in, const int* in_sizes, int n_in,
                              void* d_out, int out_size, void* d_ws, size_t ws_size,
                              hipStream_t stream)
{
    const float* h_i   = (const float*)d_in[0];
    const float* h_j   = (const float*)d_in[1];
    const float* W1    = (const float*)d_in[2];
    const float* gamma = (const float*)d_in[3];
    const float* beta  = (const float*)d_in[4];
    const float* W2    = (const float*)d_in[5];
    const float* b2    = (const float*)d_in[6];
    float* out = (float*)d_out;

    // workspace layout (~66 MB)
    float* X      = (float*)d_ws;                        // 4096*2048 fp32
    float* Z      = X + (size_t)NROWS * LATENT;          // 4096*256
    float* sums   = Z + (size_t)NROWS * PROJ;            // 2*2048
    float* sumsqs = sums + 2 * LATENT;                   // 2*2048
    float* rowsum = sumsqs + 2 * LATENT;                 // 4096
    float* scaleA = rowsum + NROWS;                      // 2*2048
    float* shiftA = scaleA + 2 * LATENT;                 // 2*2048
    float* dgA    = shiftA + 2 * LATENT;                 // 4096
    float* posA   = dgA + NROWS;                         // 4096
    unsigned short* Hb  = (unsigned short*)(posA + NROWS);         // 4096*2048 bf16
    unsigned short* W1b = Hb + (size_t)NROWS * LATENT;             // 2048*2048
    unsigned short* W2b = W1b + (size_t)LATENT * LATENT;           // 256*2048
    unsigned short* ZNb = W2b + (size_t)PROJ * LATENT;             // 4096*256
    unsigned short* Xb  = Hb;   // reuse Hb region after gemm1 is done

    // zero the atomic accumulators (sums, sumsqs, rowsum contiguous)
    hipMemsetAsync(sums, 0, (size_t)(4 * LATENT + NROWS) * sizeof(float), stream);

    cvt_kernel<<<4096, 256, 0, stream>>>(h_i, Hb, BATCH * LATENT / 4);
    cvt_kernel<<<4096, 256, 0, stream>>>(h_j, Hb + (size_t)BATCH * LATENT, BATCH * LATENT / 4);
    cvt_kernel<<<4096, 256, 0, stream>>>(W1, W1b, LATENT * LATENT / 4);
    cvt_kernel<<<512, 256, 0, stream>>>(W2, W2b, PROJ * LATENT / 4);

    gemm1_mfma<<<dim3(LATENT / 128, NROWS / 128), 256, 0, stream>>>(Hb, W1b, X);
    bn_stats_kernel<<<dim3(LATENT / 256, 32), 256, 0, stream>>>(X, sums, sumsqs);
    bn_final_kernel<<<(2 * LATENT) / 256, 256, 0, stream>>>(sums, sumsqs, gamma, beta, scaleA, shiftA);
    bnrelu_cvt_kernel<<<(NROWS * LATENT / 4) / 256, 256, 0, stream>>>(X, scaleA, shiftA, Xb);
    gemm2_mfma<<<dim3(PROJ / 64, NROWS / 128), 256, 0, stream>>>(Xb, W2b, b2, Z);
    rownorm_kernel<<<NROWS / 4, 256, 0, stream>>>(Z, ZNb);
    simlse_mfma<<<dim3(NROWS / 128, NROWS / 128), 256, 0, stream>>>(ZNb, rowsum, dgA, posA);
    loss_kernel<<<1, 256, 0, stream>>>(rowsum, dgA, posA, out);
}

// Round 3
// 212.734 us; speedup vs baseline: 3.7861x; 1.1390x over previous
//
#include <hip/hip_runtime.h>
#include <math.h>

#define BATCH   2048
#define NROWS   4096   // 2*BATCH
#define LATENT  2048
#define PROJ    256
#define TEMP_INV 2.0f      // 1/0.5
#define BN_EPS  1e-5f
#define COS_EPS 1e-8f

typedef __bf16 bf16x8 __attribute__((ext_vector_type(8)));
typedef float  f32x4  __attribute__((ext_vector_type(4)));

__device__ __forceinline__ unsigned short f2bf(float f) {
    union { float f; unsigned int u; } c; c.f = f;
    return (unsigned short)((c.u + 0x7FFFu + ((c.u >> 16) & 1u)) >> 16);
}
__device__ __forceinline__ float bf2f(unsigned short h) {
    union { unsigned int u; float f; } c; c.u = ((unsigned int)h) << 16;
    return c.f;
}

// async global->LDS, 16 bytes per lane. LDS dest is wave-uniform base + lane*16.
__device__ __forceinline__ void gl_lds16(const unsigned short* g, unsigned short* l) {
    __builtin_amdgcn_global_load_lds(
        (__attribute__((address_space(1))) void*)g,
        (__attribute__((address_space(3))) void*)l, 16, 0, 0);
}

// ---------------------------------------------------------------------------
// Fused fp32->bf16 convert of all four inputs into one contiguous bf16 region
// [Hb(h_i|h_j) | W1b | W2b]. 4 floats/thread.
// ---------------------------------------------------------------------------
#define G1 1048576   // h_i float4-groups
#define G2 2097152
#define G3 3145728
#define G4 3276800
__global__ __launch_bounds__(256) void cvt_all_kernel(
    const float* __restrict__ h_i, const float* __restrict__ h_j,
    const float* __restrict__ W1,  const float* __restrict__ W2,
    unsigned short* __restrict__ dst)
{
    int i = blockIdx.x * 256 + threadIdx.x;
    if (i >= G4) return;
    const float* src; int off;
    if (i < G1)      { src = h_i; off = i; }
    else if (i < G2) { src = h_j; off = i - G1; }
    else if (i < G3) { src = W1;  off = i - G2; }
    else             { src = W2;  off = i - G3; }
    float4 v = reinterpret_cast<const float4*>(src)[off];
    ushort4 o;
    o.x = f2bf(v.x); o.y = f2bf(v.y); o.z = f2bf(v.z); o.w = f2bf(v.w);
    reinterpret_cast<ushort4*>(dst)[i] = o;
}

// ---------------------------------------------------------------------------
// Core MFMA K-loop. 256 threads = 4 waves in 2x2. BM=WM*32, BN=WN*32, BK=32.
// Operands row-major [rows][KSTRIDE] bf16 (B^T-input GEMM); iterates KLEN.
// LDS tiles row-major [rows][32] bf16, unpadded (global_load_lds constraint).
// ---------------------------------------------------------------------------
template<int KSTRIDE, int KLEN, int WM, int WN>
__device__ __forceinline__ void mfma_loop(
    const unsigned short* __restrict__ Ab,
    const unsigned short* __restrict__ Bb,
    unsigned short* As, unsigned short* Bs,
    f32x4 acc[WM][WN], int tid)
{
    constexpr int BM = WM * 32;
    constexpr int BN = WN * 32;
    const int wid = tid >> 6, lane = tid & 63;
    const int mblk = (wid >> 1) * (WM * 16);
    const int nblk = (wid & 1) * (WN * 16);
    const int lr = lane & 15, lk = lane >> 4;
    for (int k0 = 0; k0 < KLEN; k0 += 32) {
        __syncthreads();
        #pragma unroll
        for (int u = 0; u < BM / 64; ++u) {
            int li = u * 256 + tid;
            gl_lds16(Ab + (size_t)(li >> 2) * KSTRIDE + k0 + (li & 3) * 8, As + li * 8);
        }
        #pragma unroll
        for (int u = 0; u < BN / 64; ++u) {
            int li = u * 256 + tid;
            gl_lds16(Bb + (size_t)(li >> 2) * KSTRIDE + k0 + (li & 3) * 8, Bs + li * 8);
        }
        __syncthreads();
        bf16x8 af[WM], bv[WN];
        #pragma unroll
        for (int i = 0; i < WM; ++i)
            af[i] = *reinterpret_cast<const bf16x8*>(As + (mblk + i * 16 + lr) * 32 + lk * 8);
        #pragma unroll
        for (int j = 0; j < WN; ++j)
            bv[j] = *reinterpret_cast<const bf16x8*>(Bs + (nblk + j * 16 + lr) * 32 + lk * 8);
        #pragma unroll
        for (int i = 0; i < WM; ++i)
            #pragma unroll
            for (int j = 0; j < WN; ++j)
                acc[i][j] = __builtin_amdgcn_mfma_f32_16x16x32_bf16(af[i], bv[j], acc[i][j], 0, 0, 0);
    }
}

// ---------------------------------------------------------------------------
// GEMM1: X[m][n] = sum_k H[m][k]*W1[n][k]  (M=4096, N=2048, K=2048)
// BM=64 x BN=128 -> 1024 blocks (4/CU). Epilogue: bf16 X store + fused BN
// column stats (sum, sumsq) from the fp32 accumulators.
// ---------------------------------------------------------------------------
__global__ __launch_bounds__(256) void gemm1_mfma(
    const unsigned short* __restrict__ Hb, const unsigned short* __restrict__ W1b,
    unsigned short* __restrict__ Xb, float* __restrict__ sums, float* __restrict__ sumsqs)
{
    __shared__ __align__(16) unsigned short As[64 * 32];
    __shared__ __align__(16) unsigned short Bs[128 * 32];
    const int tid = threadIdx.x;
    const int m0 = blockIdx.y * 64, n0 = blockIdx.x * 128;
    f32x4 zero = {0.f, 0.f, 0.f, 0.f};
    f32x4 acc[2][4];
    #pragma unroll
    for (int i = 0; i < 2; ++i)
        #pragma unroll
        for (int j = 0; j < 4; ++j) acc[i][j] = zero;
    mfma_loop<LATENT, LATENT, 2, 4>(Hb + (size_t)m0 * LATENT, W1b + (size_t)n0 * LATENT,
                                    As, Bs, acc, tid);
    const int wid = tid >> 6, lane = tid & 63;
    const int mblk = (wid >> 1) * 32, nblk = (wid & 1) * 64;
    const int lr = lane & 15, lq = lane >> 4;
    const int half = m0 >> 11;   // m0/BATCH
    #pragma unroll
    for (int j = 0; j < 4; ++j) {
        float s = 0.f, q = 0.f;
        #pragma unroll
        for (int i = 0; i < 2; ++i)
            #pragma unroll
            for (int r = 0; r < 4; ++r) {
                float v = acc[i][j][r];
                s += v; q += v * v;
                int row = m0 + mblk + i * 16 + lq * 4 + r;
                int col = n0 + nblk + j * 16 + lr;
                Xb[(size_t)row * LATENT + col] = f2bf(v);
            }
        // reduce the 32 rows this wave covers: lanes lane, lane^16, lane^32, lane^48
        s += __shfl_xor(s, 16, 64);  q += __shfl_xor(q, 16, 64);
        s += __shfl_xor(s, 32, 64);  q += __shfl_xor(q, 32, 64);
        if (lq == 0) {
            int col = n0 + nblk + j * 16 + lr;
            atomicAdd(&sums[half * LATENT + col], s);
            atomicAdd(&sumsqs[half * LATENT + col], q);
        }
    }
}

__global__ __launch_bounds__(256) void bn_final_kernel(
    const float* __restrict__ sums, const float* __restrict__ sumsqs,
    const float* __restrict__ gamma, const float* __restrict__ beta,
    float* __restrict__ scaleA, float* __restrict__ shiftA)
{
    const int idx = blockIdx.x * 256 + threadIdx.x;   // 0..4095
    const int c = idx & (LATENT - 1);
    float mu  = sums[idx] * (1.0f / BATCH);
    float var = sumsqs[idx] * (1.0f / BATCH) - mu * mu;
    float inv = rsqrtf(var + BN_EPS);
    float sc = gamma[c] * inv;
    scaleA[idx] = sc;
    shiftA[idx] = beta[c] - mu * sc;
}

// ---------------------------------------------------------------------------
// BN+ReLU in-place on bf16 X. 8 elems/thread.
// ---------------------------------------------------------------------------
__global__ __launch_bounds__(256) void bnrelu_kernel(
    unsigned short* __restrict__ Xb, const float* __restrict__ scaleA,
    const float* __restrict__ shiftA)
{
    int idx = (blockIdx.x * 256 + threadIdx.x) * 8;
    int row = idx >> 11;
    int col = idx & (LATENT - 1);
    int half = row >> 11;
    ushort4 a = *reinterpret_cast<const ushort4*>(Xb + idx);
    ushort4 b = *reinterpret_cast<const ushort4*>(Xb + idx + 4);
    float4 s0 = *reinterpret_cast<const float4*>(scaleA + half * LATENT + col);
    float4 s1 = *reinterpret_cast<const float4*>(scaleA + half * LATENT + col + 4);
    float4 h0 = *reinterpret_cast<const float4*>(shiftA + half * LATENT + col);
    float4 h1 = *reinterpret_cast<const float4*>(shiftA + half * LATENT + col + 4);
    ushort4 oa, ob;
    oa.x = f2bf(fmaxf(fmaf(bf2f(a.x), s0.x, h0.x), 0.f));
    oa.y = f2bf(fmaxf(fmaf(bf2f(a.y), s0.y, h0.y), 0.f));
    oa.z = f2bf(fmaxf(fmaf(bf2f(a.z), s0.z, h0.z), 0.f));
    oa.w = f2bf(fmaxf(fmaf(bf2f(a.w), s0.w, h0.w), 0.f));
    ob.x = f2bf(fmaxf(fmaf(bf2f(b.x), s1.x, h1.x), 0.f));
    ob.y = f2bf(fmaxf(fmaf(bf2f(b.y), s1.y, h1.y), 0.f));
    ob.z = f2bf(fmaxf(fmaf(bf2f(b.z), s1.z, h1.z), 0.f));
    ob.w = f2bf(fmaxf(fmaf(bf2f(b.w), s1.w, h1.w), 0.f));
    *reinterpret_cast<ushort4*>(Xb + idx) = oa;
    *reinterpret_cast<ushort4*>(Xb + idx + 4) = ob;
}

// ---------------------------------------------------------------------------
// GEMM2 split-K=4: Zp[kc][m][n] = sum_{k in chunk} Xb[m][k]*W2[n][k]
// BM=128 x BN=64 x KC=512 -> 512 blocks (2/CU).
// ---------------------------------------------------------------------------
__global__ __launch_bounds__(256) void gemm2_mfma(
    const unsigned short* __restrict__ Xb, const unsigned short* __restrict__ W2b,
    float* __restrict__ Zp)
{
    __shared__ __align__(16) unsigned short As[128 * 32];
    __shared__ __align__(16) unsigned short Bs[64 * 32];
    const int tid = threadIdx.x;
    const int m0 = blockIdx.y * 128, n0 = blockIdx.x * 64, kc = blockIdx.z;
    f32x4 zero = {0.f, 0.f, 0.f, 0.f};
    f32x4 acc[4][2];
    #pragma unroll
    for (int i = 0; i < 4; ++i) { acc[i][0] = zero; acc[i][1] = zero; }
    mfma_loop<LATENT, 512, 4, 2>(Xb + (size_t)m0 * LATENT + kc * 512,
                                 W2b + (size_t)n0 * LATENT + kc * 512, As, Bs, acc, tid);
    float* Zk = Zp + (size_t)kc * NROWS * PROJ;
    const int wid = tid >> 6, lane = tid & 63;
    const int mblk = (wid >> 1) * 64, nblk = (wid & 1) * 32;
    const int lr = lane & 15, lq = lane >> 4;
    #pragma unroll
    for (int i = 0; i < 4; ++i)
        #pragma unroll
        for (int j = 0; j < 2; ++j)
            #pragma unroll
            for (int r = 0; r < 4; ++r) {
                int row = m0 + mblk + i * 16 + lq * 4 + r;
                int col = n0 + nblk + j * 16 + lr;
                Zk[(size_t)row * PROJ + col] = acc[i][j][r];
            }
}

// ---------------------------------------------------------------------------
// Sum 4 K-partials + b2, L2-normalize row -> bf16 ZNb. One wave per row.
// ---------------------------------------------------------------------------
__global__ __launch_bounds__(256) void rownorm_kernel(
    const float* __restrict__ Zp, const float* __restrict__ b2,
    unsigned short* __restrict__ ZNb)
{
    const int wave = threadIdx.x >> 6;
    const int lane = threadIdx.x & 63;
    const int row = blockIdx.x * 4 + wave;
    float v[4];
    float sq = 0.f;
    #pragma unroll
    for (int i = 0; i < 4; ++i) {
        int col = lane + i * 64;
        float t = b2[col];
        #pragma unroll
        for (int c = 0; c < 4; ++c)
            t += Zp[(size_t)c * NROWS * PROJ + (size_t)row * PROJ + col];
        v[i] = t;
        sq += t * t;
    }
    #pragma unroll
    for (int off = 32; off > 0; off >>= 1) sq += __shfl_xor(sq, off, 64);
    float inv = 1.0f / fmaxf(sqrtf(sq), COS_EPS);
    #pragma unroll
    for (int i = 0; i < 4; ++i)
        ZNb[(size_t)row * PROJ + lane + i * 64] = f2bf(v[i] * inv);
}

// ---------------------------------------------------------------------------
// sim tile via MFMA + fused exp/rowsum/diag/pos. K=PROJ=256.
// ---------------------------------------------------------------------------
__global__ __launch_bounds__(256) void simlse_mfma(
    const unsigned short* __restrict__ ZNb, float* __restrict__ rowsum,
    float* __restrict__ dgA, float* __restrict__ posA)
{
    __shared__ __align__(16) unsigned short As[128 * 32];
    __shared__ __align__(16) unsigned short Bs[128 * 32];
    const int tid = threadIdx.x;
    const int r0 = blockIdx.y * 128, j0 = blockIdx.x * 128;
    f32x4 zero = {0.f, 0.f, 0.f, 0.f};
    f32x4 acc[4][4];
    #pragma unroll
    for (int i = 0; i < 4; ++i)
        #pragma unroll
        for (int j = 0; j < 4; ++j) acc[i][j] = zero;
    mfma_loop<PROJ, PROJ, 4, 4>(ZNb + (size_t)r0 * PROJ, ZNb + (size_t)j0 * PROJ,
                                As, Bs, acc, tid);
    const int wid = tid >> 6, lane = tid & 63;
    const int mblk = (wid >> 1) * 64, nblk = (wid & 1) * 64;
    const int lr = lane & 15, lq = lane >> 4;
    #pragma unroll
    for (int i = 0; i < 4; ++i)
        #pragma unroll
        for (int r = 0; r < 4; ++r) {
            int R = r0 + mblk + i * 16 + lq * 4 + r;
            int P = (R < BATCH) ? R + BATCH : R - BATCH;
            float t = 0.f;
            #pragma unroll
            for (int j = 0; j < 4; ++j) {
                int J = j0 + nblk + j * 16 + lr;
                float s = acc[i][j][r] * TEMP_INV;
                float e = __expf(s);
                t += e;
                if (J == R) dgA[R] = e;     // unique writer
                if (J == P) posA[R] = s;    // unique writer
            }
            t += __shfl_xor(t, 1, 64);
            t += __shfl_xor(t, 2, 64);
            t += __shfl_xor(t, 4, 64);
            t += __shfl_xor(t, 8, 64);
            if (lr == 0) atomicAdd(&rowsum[R], t);
        }
}

// loss = (1/N) * sum_r [ log(rowsum_r - diag_r) - pos_r ]
__global__ __launch_bounds__(256) void loss_kernel(
    const float* __restrict__ rowsum, const float* __restrict__ dgA,
    const float* __restrict__ posA, float* __restrict__ out)
{
    __shared__ float red[256];
    float s = 0.f;
    for (int r = threadIdx.x; r < NROWS; r += 256)
        s += logf(rowsum[r] - dgA[r]) - posA[r];
    red[threadIdx.x] = s;
    __syncthreads();
    for (int off = 128; off > 0; off >>= 1) {
        if (threadIdx.x < off) red[threadIdx.x] += red[threadIdx.x + off];
        __syncthreads();
    }
    if (threadIdx.x == 0) out[0] = red[0] * (1.0f / NROWS);
}

// ---------------------------------------------------------------------------
extern "C" void kernel_launch(void* const* d_in, const int* in_sizes, int n_in,
                              void* d_out, int out_size, void* d_ws, size_t ws_size,
                              hipStream_t stream)
{
    const float* h_i   = (const float*)d_in[0];
    const float* h_j   = (const float*)d_in[1];
    const float* W1    = (const float*)d_in[2];
    const float* gamma = (const float*)d_in[3];
    const float* beta  = (const float*)d_in[4];
    const float* W2    = (const float*)d_in[5];
    const float* b2    = (const float*)d_in[6];
    float* out = (float*)d_out;

    // workspace (~62 MB)
    float* Zp     = (float*)d_ws;                        // 4 * 4096*256 fp32
    float* sums   = Zp + (size_t)4 * NROWS * PROJ;       // 4096
    float* sumsqs = sums + 2 * LATENT;                   // 4096
    float* rowsum = sumsqs + 2 * LATENT;                 // 4096
    float* scaleA = rowsum + NROWS;                      // 4096
    float* shiftA = scaleA + 2 * LATENT;                 // 4096
    float* dgA    = shiftA + 2 * LATENT;                 // 4096
    float* posA   = dgA + NROWS;                         // 4096
    unsigned short* Hb  = (unsigned short*)(posA + NROWS);   // 4096*2048 bf16
    unsigned short* W1b = Hb + (size_t)NROWS * LATENT;       // 2048*2048
    unsigned short* W2b = W1b + (size_t)LATENT * LATENT;     // 256*2048
    unsigned short* Xb  = W2b + (size_t)PROJ * LATENT;       // 4096*2048
    unsigned short* ZNb = Xb + (size_t)NROWS * LATENT;       // 4096*256

    // zero atomic accumulators (sums, sumsqs, rowsum contiguous = 12288 floats)
    hipMemsetAsync(sums, 0, (size_t)(4 * LATENT + NROWS) * sizeof(float), stream);

    cvt_all_kernel<<<(G4 + 255) / 256, 256, 0, stream>>>(h_i, h_j, W1, W2, Hb);
    gemm1_mfma<<<dim3(LATENT / 128, NROWS / 64), 256, 0, stream>>>(Hb, W1b, Xb, sums, sumsqs);
    bn_final_kernel<<<(2 * LATENT) / 256, 256, 0, stream>>>(sums, sumsqs, gamma, beta, scaleA, shiftA);
    bnrelu_kernel<<<(NROWS * LATENT / 8) / 256, 256, 0, stream>>>(Xb, scaleA, shiftA);
    gemm2_mfma<<<dim3(PROJ / 64, NROWS / 128, 4), 256, 0, stream>>>(Xb, W2b, Zp);
    rownorm_kernel<<<NROWS / 4, 256, 0, stream>>>(Zp, b2, ZNb);
    simlse_mfma<<<dim3(NROWS / 128, NROWS / 128), 256, 0, stream>>>(ZNb, rowsum, dgA, posA);
    loss_kernel<<<1, 256, 0, stream>>>(rowsum, dgA, posA, out);
}